// Round 10
// baseline (277.836 us; speedup 1.0000x reference)
//
#include <hip/hip_runtime.h>
#include <hip/hip_bf16.h>
#include <math.h>

// ---------------------------------------------------------------------------
// GCN 2-layer forward on MI355X (gfx950).
// Inputs: x[N,128] f32, edge_index[2,E] int32, W1[128,128], b1[128],
//         W2[128,40], b2[40].  Output: log_softmax [N,40] f32.
// Round 7: CSR build = 1021-bucket counting sort with LDS cursors.
//   Round-6 lesson: GLOBAL cursor atomics write through the coherence point
//   (~16B/op -> 65MB writes for 6.4MB payload) and are latency-bound at low
//   occupancy. No routing fixes that. Fix: buckets of RB=98 rows; per-bucket
//   blocks keep cursors/histograms in LDS; deg and ecol are written with
//   plain coalesced/streaming stores. Only ~200K global atomics remain
//   (per-block bucket tail-appends in the binning pass).
//   + k_pull1 edge loop 4x unrolled (gather latency hiding).
// ---------------------------------------------------------------------------

#define TILE_A 8192   // edges per binning block
#define RB 98         // rows per bucket (1021 buckets for N=100000)

struct f8 { float v[8]; };

__device__ inline f8 unpack8(uint4 u) {
    f8 r;
    r.v[0] = __uint_as_float(u.x << 16);
    r.v[1] = __uint_as_float(u.x & 0xffff0000u);
    r.v[2] = __uint_as_float(u.y << 16);
    r.v[3] = __uint_as_float(u.y & 0xffff0000u);
    r.v[4] = __uint_as_float(u.z << 16);
    r.v[5] = __uint_as_float(u.z & 0xffff0000u);
    r.v[6] = __uint_as_float(u.w << 16);
    r.v[7] = __uint_as_float(u.w & 0xffff0000u);
    return r;
}

__device__ inline unsigned pack2(float a, float b) {  // a -> low half (RNE)
    __hip_bfloat16 ha = __float2bfloat16(a);
    __hip_bfloat16 hb = __float2bfloat16(b);
    unsigned short sa = *(unsigned short*)&ha;
    unsigned short sb = *(unsigned short*)&hb;
    return (unsigned)sa | ((unsigned)sb << 16);
}

__global__ __launch_bounds__(256) void k_zero(int* __restrict__ p, int n) {
    int i = blockIdx.x * 256 + threadIdx.x;
    if (i < n) p[i] = 0;
}

// bucket histogram over row index (LDS-aggregated)
__global__ __launch_bounds__(256) void k_prebin(const int* __restrict__ row,
                                                int* __restrict__ bktcnt,
                                                int E, int nbkt) {
    __shared__ int h[1024];
    int t = threadIdx.x;
    for (int j = t; j < 1024; j += 256) h[j] = 0;
    __syncthreads();
    int base = blockIdx.x * TILE_A;
    int lim = min(base + TILE_A, E);
    for (int i = base + t; i < lim; i += 256) atomicAdd(&h[row[i] / RB], 1);
    __syncthreads();
    for (int j = t; j < nbkt; j += 256)
        if (h[j]) atomicAdd(&bktcnt[j], h[j]);
}

// single-block scan of bucket counts -> gbase (exclusive), gcur (= gbase)
__global__ __launch_bounds__(1024) void k_bscan(const int* __restrict__ bktcnt,
                                                int* __restrict__ gbase,
                                                int* __restrict__ gcur, int nbkt) {
    __shared__ int l[1024];
    int t = threadIdx.x;
    int v = (t < nbkt) ? bktcnt[t] : 0;
    l[t] = v;
    __syncthreads();
#pragma unroll
    for (int o = 1; o < 1024; o <<= 1) {
        int u = (t >= o) ? l[t - o] : 0;
        __syncthreads();
        l[t] += u;
        __syncthreads();
    }
    if (t < nbkt) {
        int excl = l[t] - v;
        gbase[t] = excl;
        gcur[t] = excl;
        if (t == nbkt - 1) gbase[nbkt] = l[t];
    }
}

// partition edges into buckets as (r,c) records; LDS histogram ->
// one global tail-append atomic per (block, bucket) -> LDS cursor scatter.
__global__ __launch_bounds__(256) void k_binA(const int* __restrict__ ei,
                                              int* __restrict__ gcur,
                                              int2* __restrict__ brec, int E) {
    __shared__ int h[1024];
    __shared__ int cur[1024];
    int t = threadIdx.x;
    for (int j = t; j < 1024; j += 256) h[j] = 0;
    __syncthreads();
    int base = blockIdx.x * TILE_A;
    int lim = min(base + TILE_A, E);
    for (int i = base + t; i < lim; i += 256) atomicAdd(&h[ei[i] / RB], 1);
    __syncthreads();
    for (int j = t; j < 1024; j += 256)
        cur[j] = h[j] ? atomicAdd(&gcur[j], h[j]) : 0;
    __syncthreads();
    for (int i = base + t; i < lim; i += 256) {
        int r = ei[i];
        int pos = atomicAdd(&cur[r / RB], 1);
        brec[pos] = make_int2(r, ei[E + i]);
    }
}

// per-bucket degree count: LDS histogram, coalesced non-atomic deg write (+1 self loop)
__global__ __launch_bounds__(256) void k_count3(const int2* __restrict__ brec,
                                                const int* __restrict__ gbase,
                                                int* __restrict__ deg, int N) {
    __shared__ int h[RB];
    int k = blockIdx.x;
    int t = threadIdx.x;
    if (t < RB) h[t] = 0;
    __syncthreads();
    int s = gbase[k], e = gbase[k + 1];
    int r0 = k * RB;
    for (int i = s + t; i < e; i += 256) atomicAdd(&h[brec[i].x - r0], 1);
    __syncthreads();
    if (t < RB && r0 + t < N) deg[r0 + t] = h[t] + 1;
}

// block-level inclusive scan of (deg-1); partials to bsum; also dinv = rsqrt(deg)
__global__ __launch_bounds__(256) void k_scan1(const int* __restrict__ deg,
                                               int* __restrict__ tmp,
                                               int* __restrict__ bsum,
                                               float* __restrict__ dinv, int N) {
    __shared__ int l[256];
    int t = threadIdx.x;
    int i = blockIdx.x * 256 + t;
    int d = (i < N) ? deg[i] : 1;
    if (i < N) dinv[i] = rsqrtf((float)d);
    l[t] = (i < N) ? d - 1 : 0;
    __syncthreads();
#pragma unroll
    for (int o = 1; o < 256; o <<= 1) {
        int u = (t >= o) ? l[t - o] : 0;
        __syncthreads();
        l[t] += u;
        __syncthreads();
    }
    if (i < N) tmp[i] = l[t];
    if (t == 255) bsum[blockIdx.x] = l[255];
}

__global__ __launch_bounds__(1024) void k_scan2(int* __restrict__ bsum, int nb) {
    __shared__ int l[1024];
    int t = threadIdx.x;
    l[t] = (t < nb) ? bsum[t] : 0;
    __syncthreads();
#pragma unroll
    for (int o = 1; o < 1024; o <<= 1) {
        int u = (t >= o) ? l[t - o] : 0;
        __syncthreads();
        l[t] += u;
        __syncthreads();
    }
    if (t < nb) bsum[t] = l[t];
}

__global__ __launch_bounds__(256) void k_scan3(const int* __restrict__ deg,
                                               const int* __restrict__ tmp,
                                               const int* __restrict__ bsum,
                                               int* __restrict__ row_ptr, int N, int E) {
    int i = blockIdx.x * 256 + threadIdx.x;
    if (i >= N) return;
    int excl = tmp[i] - (deg[i] - 1) + (blockIdx.x ? bsum[blockIdx.x - 1] : 0);
    row_ptr[i] = excl;
    if (i == 0) row_ptr[N] = E;
}

// per-bucket CSR scatter: cursors in LDS, writes confined to the bucket's
// contiguous ecol window (~6KB) -> streaming, no global atomics.
__global__ __launch_bounds__(256) void k_csr3(const int2* __restrict__ brec,
                                              const int* __restrict__ gbase,
                                              const int* __restrict__ row_ptr,
                                              int* __restrict__ ecol, int N) {
    __shared__ int cur[RB];
    int k = blockIdx.x;
    int t = threadIdx.x;
    int r0 = k * RB;
    if (t < RB) cur[t] = (r0 + t < N) ? row_ptr[r0 + t] : 0;
    __syncthreads();
    int s = gbase[k], e = gbase[k + 1];
    for (int i = s + t; i < e; i += 256) {
        int2 rc = brec[i];
        int pos = atomicAdd(&cur[rc.x - r0], 1);
        ecol[pos] = rc.y;
    }
}

// T[N,128](bf16) = X[N,128] @ W1. 32 nodes/block; thread: 4 nodes x 1 float4-col.
__global__ __launch_bounds__(256) void k_gemm1(const float* __restrict__ x,
                                               const float* __restrict__ W,
                                               unsigned* __restrict__ Tb, int N) {
    __shared__ float Wl[128 * 128];
    __shared__ float xl[32 * 128];
    int t = threadIdx.x;
    float4* Wl4 = (float4*)Wl;
    const float4* W4 = (const float4*)W;
#pragma unroll
    for (int i = 0; i < 16; ++i) Wl4[t + 256 * i] = W4[t + 256 * i];
    long long nbase = (long long)blockIdx.x * 32;
    float4* xl4 = (float4*)xl;
    const float4* x4 = (const float4*)x;
#pragma unroll
    for (int i = 0; i < 4; ++i) {
        int idx = t + 256 * i;
        long long n = nbase + idx / 32;
        if (n >= N) n = N - 1;
        xl4[idx] = x4[n * 32 + (idx & 31)];
    }
    __syncthreads();

    int fq = t & 31;
    int ng = t >> 5;
    float4 acc[4];
#pragma unroll
    for (int i = 0; i < 4; ++i) acc[i] = make_float4(0.f, 0.f, 0.f, 0.f);

#pragma unroll 8
    for (int k = 0; k < 128; ++k) {
        float4 w = Wl4[k * 32 + fq];
#pragma unroll
        for (int i = 0; i < 4; ++i) {
            float xv = xl[(ng + 8 * i) * 128 + k];
            acc[i].x = fmaf(xv, w.x, acc[i].x);
            acc[i].y = fmaf(xv, w.y, acc[i].y);
            acc[i].z = fmaf(xv, w.z, acc[i].z);
            acc[i].w = fmaf(xv, w.w, acc[i].w);
        }
    }
    uint2* T2 = (uint2*)Tb;
#pragma unroll
    for (int i = 0; i < 4; ++i) {
        long long n = nbase + ng + 8 * i;
        if (n < N) {
            uint2 o;
            o.x = pack2(acc[i].x, acc[i].y);
            o.y = pack2(acc[i].z, acc[i].w);
            T2[n * 32 + fq] = o;
        }
    }
}

// U[n](bf16) = relu( dinv^2*T[n] + sum_e dinv[n]*dinv[c]*T[c] + b1 )
// 16 lanes/node, 8 bf16 features per lane (uint4); edge loop 4x unrolled.
__global__ __launch_bounds__(256) void k_pull1(const uint4* __restrict__ Tb,
                                               const float* __restrict__ dinv,
                                               const int* __restrict__ row_ptr,
                                               const int* __restrict__ ecol,
                                               const float* __restrict__ b,
                                               uint4* __restrict__ Ub, int N) {
    int tid = blockIdx.x * 256 + threadIdx.x;
    int n = tid >> 4;
    if (n >= N) return;
    int q = tid & 15;

    float dn = dinv[n];
    float ss = dn * dn;
    f8 s8 = unpack8(Tb[(size_t)n * 16 + q]);
    float acc[8];
#pragma unroll
    for (int j = 0; j < 8; ++j) acc[j] = s8.v[j] * ss;

    int beg = row_ptr[n], end = row_ptr[n + 1];
    int i = beg;
    for (; i + 3 < end; i += 4) {
        int c0 = ecol[i], c1 = ecol[i + 1], c2 = ecol[i + 2], c3 = ecol[i + 3];
        float w0 = dn * dinv[c0];
        float w1 = dn * dinv[c1];
        float w2 = dn * dinv[c2];
        float w3 = dn * dinv[c3];
        uint4 g0 = Tb[(size_t)c0 * 16 + q];
        uint4 g1 = Tb[(size_t)c1 * 16 + q];
        uint4 g2 = Tb[(size_t)c2 * 16 + q];
        uint4 g3 = Tb[(size_t)c3 * 16 + q];
        f8 a0 = unpack8(g0);
        f8 a1 = unpack8(g1);
        f8 a2 = unpack8(g2);
        f8 a3 = unpack8(g3);
#pragma unroll
        for (int j = 0; j < 8; ++j) acc[j] = fmaf(w0, a0.v[j], acc[j]);
#pragma unroll
        for (int j = 0; j < 8; ++j) acc[j] = fmaf(w1, a1.v[j], acc[j]);
#pragma unroll
        for (int j = 0; j < 8; ++j) acc[j] = fmaf(w2, a2.v[j], acc[j]);
#pragma unroll
        for (int j = 0; j < 8; ++j) acc[j] = fmaf(w3, a3.v[j], acc[j]);
    }
    for (; i < end; ++i) {
        int c0 = ecol[i];
        float w0 = dn * dinv[c0];
        f8 a0 = unpack8(Tb[(size_t)c0 * 16 + q]);
#pragma unroll
        for (int j = 0; j < 8; ++j) acc[j] = fmaf(w0, a0.v[j], acc[j]);
    }

    float4 b0 = ((const float4*)b)[q * 2];
    float4 b1v = ((const float4*)b)[q * 2 + 1];
    acc[0] = fmaxf(acc[0] + b0.x, 0.f);
    acc[1] = fmaxf(acc[1] + b0.y, 0.f);
    acc[2] = fmaxf(acc[2] + b0.z, 0.f);
    acc[3] = fmaxf(acc[3] + b0.w, 0.f);
    acc[4] = fmaxf(acc[4] + b1v.x, 0.f);
    acc[5] = fmaxf(acc[5] + b1v.y, 0.f);
    acc[6] = fmaxf(acc[6] + b1v.z, 0.f);
    acc[7] = fmaxf(acc[7] + b1v.w, 0.f);

    uint4 o;
    o.x = pack2(acc[0], acc[1]);
    o.y = pack2(acc[2], acc[3]);
    o.z = pack2(acc[4], acc[5]);
    o.w = pack2(acc[6], acc[7]);
    Ub[(size_t)n * 16 + q] = o;
}

// H2[N,40](bf16) = U[N,128](bf16) @ W2[128,40]. One thread: 2 nodes x 40 classes.
__global__ __launch_bounds__(256) void k_gemm2(const uint4* __restrict__ Ub,
                                               const float* __restrict__ W2,
                                               uint4* __restrict__ H2b, int N) {
    __shared__ float Wl[128 * 40];
    int t = threadIdx.x;
    float4* Wl4 = (float4*)Wl;
    const float4* W4 = (const float4*)W2;
#pragma unroll
    for (int i = 0; i < 5; ++i) Wl4[t + 256 * i] = W4[t + 256 * i];
    __syncthreads();

    int n0 = blockIdx.x * 512 + t;
    int n1 = n0 + 256;
    int n0c = n0 < N ? n0 : N - 1;
    int n1c = n1 < N ? n1 : N - 1;
    float a0[40], a1[40];
#pragma unroll
    for (int c = 0; c < 40; ++c) { a0[c] = 0.f; a1[c] = 0.f; }

    for (int k8 = 0; k8 < 16; ++k8) {
        f8 xa = unpack8(Ub[(size_t)n0c * 16 + k8]);
        f8 xb = unpack8(Ub[(size_t)n1c * 16 + k8]);
#pragma unroll
        for (int j = 0; j < 8; ++j) {
            float xaj = xa.v[j];
            float xbj = xb.v[j];
            int k = k8 * 8 + j;
#pragma unroll
            for (int cq = 0; cq < 10; ++cq) {
                float4 w = Wl4[k * 10 + cq];
                a0[cq * 4 + 0] = fmaf(xaj, w.x, a0[cq * 4 + 0]);
                a0[cq * 4 + 1] = fmaf(xaj, w.y, a0[cq * 4 + 1]);
                a0[cq * 4 + 2] = fmaf(xaj, w.z, a0[cq * 4 + 2]);
                a0[cq * 4 + 3] = fmaf(xaj, w.w, a0[cq * 4 + 3]);
                a1[cq * 4 + 0] = fmaf(xbj, w.x, a1[cq * 4 + 0]);
                a1[cq * 4 + 1] = fmaf(xbj, w.y, a1[cq * 4 + 1]);
                a1[cq * 4 + 2] = fmaf(xbj, w.z, a1[cq * 4 + 2]);
                a1[cq * 4 + 3] = fmaf(xbj, w.w, a1[cq * 4 + 3]);
            }
        }
    }
    if (n0 < N) {
#pragma unroll
        for (int g = 0; g < 5; ++g) {
            uint4 o;
            o.x = pack2(a0[g * 8 + 0], a0[g * 8 + 1]);
            o.y = pack2(a0[g * 8 + 2], a0[g * 8 + 3]);
            o.z = pack2(a0[g * 8 + 4], a0[g * 8 + 5]);
            o.w = pack2(a0[g * 8 + 6], a0[g * 8 + 7]);
            H2b[(size_t)n0 * 5 + g] = o;
        }
    }
    if (n1 < N) {
#pragma unroll
        for (int g = 0; g < 5; ++g) {
            uint4 o;
            o.x = pack2(a1[g * 8 + 0], a1[g * 8 + 1]);
            o.y = pack2(a1[g * 8 + 2], a1[g * 8 + 3]);
            o.z = pack2(a1[g * 8 + 4], a1[g * 8 + 5]);
            o.w = pack2(a1[g * 8 + 6], a1[g * 8 + 7]);
            H2b[(size_t)n1 * 5 + g] = o;
        }
    }
}

// out[n] = log_softmax( dinv^2*H2[n] + sum dinv[n]*dinv[c]*H2[c] + b2 )
// 8 lanes/node; lanes q<5 hold 8 classes each (uint4 of bf16).
__global__ __launch_bounds__(256) void k_pull2(const uint4* __restrict__ H2b,
                                               const float* __restrict__ dinv,
                                               const int* __restrict__ row_ptr,
                                               const int* __restrict__ ecol,
                                               const float* __restrict__ b2,
                                               float* __restrict__ out, int N) {
    int tid = blockIdx.x * 256 + threadIdx.x;
    int n = tid >> 3;
    if (n >= N) return;
    int q = tid & 7;
    bool act = q < 5;

    float dn = dinv[n];
    float ss = dn * dn;
    float acc[8];
#pragma unroll
    for (int j = 0; j < 8; ++j) acc[j] = 0.f;
    if (act) {
        f8 s8 = unpack8(H2b[(size_t)n * 5 + q]);
#pragma unroll
        for (int j = 0; j < 8; ++j) acc[j] = s8.v[j] * ss;
    }
    int beg = row_ptr[n], end = row_ptr[n + 1];
    for (int i = beg; i < end; ++i) {
        int c = ecol[i];
        float w = dn * dinv[c];
        if (act) {
            f8 a = unpack8(H2b[(size_t)c * 5 + q]);
#pragma unroll
            for (int j = 0; j < 8; ++j) acc[j] = fmaf(w, a.v[j], acc[j]);
        }
    }
    if (act) {
        float4 b0 = ((const float4*)b2)[q * 2];
        float4 b1v = ((const float4*)b2)[q * 2 + 1];
        acc[0] += b0.x; acc[1] += b0.y; acc[2] += b0.z; acc[3] += b0.w;
        acc[4] += b1v.x; acc[5] += b1v.y; acc[6] += b1v.z; acc[7] += b1v.w;
    }
    float m = -INFINITY;
    if (act) {
#pragma unroll
        for (int j = 0; j < 8; ++j) m = fmaxf(m, acc[j]);
    }
#pragma unroll
    for (int o = 4; o > 0; o >>= 1) m = fmaxf(m, __shfl_xor(m, o, 8));
    float e = 0.f;
    if (act) {
#pragma unroll
        for (int j = 0; j < 8; ++j) e += expf(acc[j] - m);
    }
#pragma unroll
    for (int o = 4; o > 0; o >>= 1) e += __shfl_xor(e, o, 8);
    float lg = m + logf(e);
    if (act) {
        float4* o4 = (float4*)out;
        o4[(size_t)n * 10 + q * 2] =
            make_float4(acc[0] - lg, acc[1] - lg, acc[2] - lg, acc[3] - lg);
        o4[(size_t)n * 10 + q * 2 + 1] =
            make_float4(acc[4] - lg, acc[5] - lg, acc[6] - lg, acc[7] - lg);
    }
}

extern "C" void kernel_launch(void* const* d_in, const int* in_sizes, int n_in,
                              void* d_out, int out_size, void* d_ws, size_t ws_size,
                              hipStream_t stream) {
    const float* x  = (const float*)d_in[0];
    const int*   ei = (const int*)d_in[1];   // integer inputs arrive as int32
    const float* W1 = (const float*)d_in[2];
    const float* b1 = (const float*)d_in[3];
    const float* W2 = (const float*)d_in[4];
    const float* b2 = (const float*)d_in[5];
    float* out = (float*)d_out;

    const int N = in_sizes[0] / 128;  // 100000
    const int E = in_sizes[1] / 2;    // 1600000
    const int nbkt = (N + RB - 1) / RB;  // 1021 (<= 1024 required)

    // workspace layout (~83 MB)
    char* ws = (char*)d_ws;
    int*   deg     = (int*)(ws);                          // N ints
    float* dinv    = (float*)(ws + (512 << 10));          // N f32
    int*   row_ptr = (int*)(ws + (1 << 20));              // N+1
    int*   bsum    = (int*)(ws + (1536 << 10));           // <=1024
    int*   tmp     = (int*)(ws + (1600 << 10));           // N ints
    int*   bktcnt  = (int*)(ws + (2100 << 10));           // 1024
    int*   gcur    = (int*)(ws + (2100 << 10) + 4096);    // 1024
    int*   gbase   = (int*)(ws + (2100 << 10) + 8192);    // 1025
    int*   ecol    = (int*)(ws + (3 << 20));              // E ints = 6.4 MB
    int2*  brec    = (int2*)(ws + (10 << 20));            // E int2 = 12.8 MB
    uint4* H2b     = (uint4*)(ws + (23 << 20));           // N*40 bf16 = 8 MB
    unsigned* Tb   = (unsigned*)(ws + (31 << 20));        // N*128 bf16 = 25.6 MB
    uint4* Ub      = (uint4*)(ws + (57 << 20));           // N*128 bf16 = 25.6 MB

    int nb = (N + 255) / 256;
    int na = (E + TILE_A - 1) / TILE_A;

    k_zero<<<4, 256, 0, stream>>>(bktcnt, 1024);
    k_prebin<<<na, 256, 0, stream>>>(ei, bktcnt, E, nbkt);
    k_bscan<<<1, 1024, 0, stream>>>(bktcnt, gbase, gcur, nbkt);
    k_binA<<<na, 256, 0, stream>>>(ei, gcur, brec, E);
    k_count3<<<nbkt, 256, 0, stream>>>(brec, gbase, deg, N);
    k_scan1<<<nb, 256, 0, stream>>>(deg, tmp, bsum, dinv, N);
    k_scan2<<<1, 1024, 0, stream>>>(bsum, nb);
    k_scan3<<<nb, 256, 0, stream>>>(deg, tmp, bsum, row_ptr, N, E);
    k_csr3<<<nbkt, 256, 0, stream>>>(brec, gbase, row_ptr, ecol, N);

    k_gemm1<<<(N + 31) / 32, 256, 0, stream>>>(x, W1, Tb, N);
    k_pull1<<<((long long)N * 16 + 255) / 256, 256, 0, stream>>>(
        (const uint4*)Tb, dinv, row_ptr, ecol, b1, Ub, N);
    k_gemm2<<<(N + 511) / 512, 256, 0, stream>>>(Ub, W2, H2b, N);
    k_pull2<<<((long long)N * 8 + 255) / 256, 256, 0, stream>>>(
        H2b, dinv, row_ptr, ecol, b2, out, N);
}

// Round 11
// 277.389 us; speedup vs baseline: 1.0016x; 1.0016x over previous
//
#include <hip/hip_runtime.h>
#include <hip/hip_bf16.h>
#include <math.h>

// ---------------------------------------------------------------------------
// GCN 2-layer forward on MI355X (gfx950).
// Inputs: x[N,128] f32, edge_index[2,E] int32, W1[128,128], b1[128],
//         W2[128,40], b2[40].  Output: log_softmax [N,40] f32.
// Round 7: CSR build = 1021-bucket counting sort with LDS cursors.
//   Round-6 lesson: GLOBAL cursor atomics write through the coherence point
//   (~16B/op -> 65MB writes for 6.4MB payload) and are latency-bound at low
//   occupancy. No routing fixes that. Fix: buckets of RB=98 rows; per-bucket
//   blocks keep cursors/histograms in LDS; deg and ecol are written with
//   plain coalesced/streaming stores. Only ~200K global atomics remain
//   (per-block bucket tail-appends in the binning pass).
//   + k_pull1 edge loop 4x unrolled (gather latency hiding).
// ---------------------------------------------------------------------------

#define TILE_A 8192   // edges per binning block
#define RB 98         // rows per bucket (1021 buckets for N=100000)

struct f8 { float v[8]; };

__device__ inline f8 unpack8(uint4 u) {
    f8 r;
    r.v[0] = __uint_as_float(u.x << 16);
    r.v[1] = __uint_as_float(u.x & 0xffff0000u);
    r.v[2] = __uint_as_float(u.y << 16);
    r.v[3] = __uint_as_float(u.y & 0xffff0000u);
    r.v[4] = __uint_as_float(u.z << 16);
    r.v[5] = __uint_as_float(u.z & 0xffff0000u);
    r.v[6] = __uint_as_float(u.w << 16);
    r.v[7] = __uint_as_float(u.w & 0xffff0000u);
    return r;
}

__device__ inline unsigned pack2(float a, float b) {  // a -> low half (RNE)
    __hip_bfloat16 ha = __float2bfloat16(a);
    __hip_bfloat16 hb = __float2bfloat16(b);
    unsigned short sa = *(unsigned short*)&ha;
    unsigned short sb = *(unsigned short*)&hb;
    return (unsigned)sa | ((unsigned)sb << 16);
}

__global__ __launch_bounds__(256) void k_zero(int* __restrict__ p, int n) {
    int i = blockIdx.x * 256 + threadIdx.x;
    if (i < n) p[i] = 0;
}

// bucket histogram over row index (LDS-aggregated)
__global__ __launch_bounds__(256) void k_prebin(const int* __restrict__ row,
                                                int* __restrict__ bktcnt,
                                                int E, int nbkt) {
    __shared__ int h[1024];
    int t = threadIdx.x;
    for (int j = t; j < 1024; j += 256) h[j] = 0;
    __syncthreads();
    int base = blockIdx.x * TILE_A;
    int lim = min(base + TILE_A, E);
    for (int i = base + t; i < lim; i += 256) atomicAdd(&h[row[i] / RB], 1);
    __syncthreads();
    for (int j = t; j < nbkt; j += 256)
        if (h[j]) atomicAdd(&bktcnt[j], h[j]);
}

// single-block scan of bucket counts -> gbase (exclusive), gcur (= gbase)
__global__ __launch_bounds__(1024) void k_bscan(const int* __restrict__ bktcnt,
                                                int* __restrict__ gbase,
                                                int* __restrict__ gcur, int nbkt) {
    __shared__ int l[1024];
    int t = threadIdx.x;
    int v = (t < nbkt) ? bktcnt[t] : 0;
    l[t] = v;
    __syncthreads();
#pragma unroll
    for (int o = 1; o < 1024; o <<= 1) {
        int u = (t >= o) ? l[t - o] : 0;
        __syncthreads();
        l[t] += u;
        __syncthreads();
    }
    if (t < nbkt) {
        int excl = l[t] - v;
        gbase[t] = excl;
        gcur[t] = excl;
        if (t == nbkt - 1) gbase[nbkt] = l[t];
    }
}

// partition edges into buckets as (r,c) records; LDS histogram ->
// one global tail-append atomic per (block, bucket) -> LDS cursor scatter.
__global__ __launch_bounds__(256) void k_binA(const int* __restrict__ ei,
                                              int* __restrict__ gcur,
                                              int2* __restrict__ brec, int E) {
    __shared__ int h[1024];
    __shared__ int cur[1024];
    int t = threadIdx.x;
    for (int j = t; j < 1024; j += 256) h[j] = 0;
    __syncthreads();
    int base = blockIdx.x * TILE_A;
    int lim = min(base + TILE_A, E);
    for (int i = base + t; i < lim; i += 256) atomicAdd(&h[ei[i] / RB], 1);
    __syncthreads();
    for (int j = t; j < 1024; j += 256)
        cur[j] = h[j] ? atomicAdd(&gcur[j], h[j]) : 0;
    __syncthreads();
    for (int i = base + t; i < lim; i += 256) {
        int r = ei[i];
        int pos = atomicAdd(&cur[r / RB], 1);
        brec[pos] = make_int2(r, ei[E + i]);
    }
}

// per-bucket degree count: LDS histogram, coalesced non-atomic deg write (+1 self loop)
__global__ __launch_bounds__(256) void k_count3(const int2* __restrict__ brec,
                                                const int* __restrict__ gbase,
                                                int* __restrict__ deg, int N) {
    __shared__ int h[RB];
    int k = blockIdx.x;
    int t = threadIdx.x;
    if (t < RB) h[t] = 0;
    __syncthreads();
    int s = gbase[k], e = gbase[k + 1];
    int r0 = k * RB;
    for (int i = s + t; i < e; i += 256) atomicAdd(&h[brec[i].x - r0], 1);
    __syncthreads();
    if (t < RB && r0 + t < N) deg[r0 + t] = h[t] + 1;
}

// block-level inclusive scan of (deg-1); partials to bsum; also dinv = rsqrt(deg)
__global__ __launch_bounds__(256) void k_scan1(const int* __restrict__ deg,
                                               int* __restrict__ tmp,
                                               int* __restrict__ bsum,
                                               float* __restrict__ dinv, int N) {
    __shared__ int l[256];
    int t = threadIdx.x;
    int i = blockIdx.x * 256 + t;
    int d = (i < N) ? deg[i] : 1;
    if (i < N) dinv[i] = rsqrtf((float)d);
    l[t] = (i < N) ? d - 1 : 0;
    __syncthreads();
#pragma unroll
    for (int o = 1; o < 256; o <<= 1) {
        int u = (t >= o) ? l[t - o] : 0;
        __syncthreads();
        l[t] += u;
        __syncthreads();
    }
    if (i < N) tmp[i] = l[t];
    if (t == 255) bsum[blockIdx.x] = l[255];
}

__global__ __launch_bounds__(1024) void k_scan2(int* __restrict__ bsum, int nb) {
    __shared__ int l[1024];
    int t = threadIdx.x;
    l[t] = (t < nb) ? bsum[t] : 0;
    __syncthreads();
#pragma unroll
    for (int o = 1; o < 1024; o <<= 1) {
        int u = (t >= o) ? l[t - o] : 0;
        __syncthreads();
        l[t] += u;
        __syncthreads();
    }
    if (t < nb) bsum[t] = l[t];
}

__global__ __launch_bounds__(256) void k_scan3(const int* __restrict__ deg,
                                               const int* __restrict__ tmp,
                                               const int* __restrict__ bsum,
                                               int* __restrict__ row_ptr, int N, int E) {
    int i = blockIdx.x * 256 + threadIdx.x;
    if (i >= N) return;
    int excl = tmp[i] - (deg[i] - 1) + (blockIdx.x ? bsum[blockIdx.x - 1] : 0);
    row_ptr[i] = excl;
    if (i == 0) row_ptr[N] = E;
}

// per-bucket CSR scatter: cursors in LDS, writes confined to the bucket's
// contiguous ecol window (~6KB) -> streaming, no global atomics.
__global__ __launch_bounds__(256) void k_csr3(const int2* __restrict__ brec,
                                              const int* __restrict__ gbase,
                                              const int* __restrict__ row_ptr,
                                              int* __restrict__ ecol, int N) {
    __shared__ int cur[RB];
    int k = blockIdx.x;
    int t = threadIdx.x;
    int r0 = k * RB;
    if (t < RB) cur[t] = (r0 + t < N) ? row_ptr[r0 + t] : 0;
    __syncthreads();
    int s = gbase[k], e = gbase[k + 1];
    for (int i = s + t; i < e; i += 256) {
        int2 rc = brec[i];
        int pos = atomicAdd(&cur[rc.x - r0], 1);
        ecol[pos] = rc.y;
    }
}

// T[N,128](bf16) = X[N,128] @ W1. 32 nodes/block; thread: 4 nodes x 1 float4-col.
__global__ __launch_bounds__(256) void k_gemm1(const float* __restrict__ x,
                                               const float* __restrict__ W,
                                               unsigned* __restrict__ Tb, int N) {
    __shared__ float Wl[128 * 128];
    __shared__ float xl[32 * 128];
    int t = threadIdx.x;
    float4* Wl4 = (float4*)Wl;
    const float4* W4 = (const float4*)W;
#pragma unroll
    for (int i = 0; i < 16; ++i) Wl4[t + 256 * i] = W4[t + 256 * i];
    long long nbase = (long long)blockIdx.x * 32;
    float4* xl4 = (float4*)xl;
    const float4* x4 = (const float4*)x;
#pragma unroll
    for (int i = 0; i < 4; ++i) {
        int idx = t + 256 * i;
        long long n = nbase + idx / 32;
        if (n >= N) n = N - 1;
        xl4[idx] = x4[n * 32 + (idx & 31)];
    }
    __syncthreads();

    int fq = t & 31;
    int ng = t >> 5;
    float4 acc[4];
#pragma unroll
    for (int i = 0; i < 4; ++i) acc[i] = make_float4(0.f, 0.f, 0.f, 0.f);

#pragma unroll 8
    for (int k = 0; k < 128; ++k) {
        float4 w = Wl4[k * 32 + fq];
#pragma unroll
        for (int i = 0; i < 4; ++i) {
            float xv = xl[(ng + 8 * i) * 128 + k];
            acc[i].x = fmaf(xv, w.x, acc[i].x);
            acc[i].y = fmaf(xv, w.y, acc[i].y);
            acc[i].z = fmaf(xv, w.z, acc[i].z);
            acc[i].w = fmaf(xv, w.w, acc[i].w);
        }
    }
    uint2* T2 = (uint2*)Tb;
#pragma unroll
    for (int i = 0; i < 4; ++i) {
        long long n = nbase + ng + 8 * i;
        if (n < N) {
            uint2 o;
            o.x = pack2(acc[i].x, acc[i].y);
            o.y = pack2(acc[i].z, acc[i].w);
            T2[n * 32 + fq] = o;
        }
    }
}

// U[n](bf16) = relu( dinv^2*T[n] + sum_e dinv[n]*dinv[c]*T[c] + b1 )
// 16 lanes/node, 8 bf16 features per lane (uint4); edge loop 4x unrolled.
__global__ __launch_bounds__(256) void k_pull1(const uint4* __restrict__ Tb,
                                               const float* __restrict__ dinv,
                                               const int* __restrict__ row_ptr,
                                               const int* __restrict__ ecol,
                                               const float* __restrict__ b,
                                               uint4* __restrict__ Ub, int N) {
    int tid = blockIdx.x * 256 + threadIdx.x;
    int n = tid >> 4;
    if (n >= N) return;
    int q = tid & 15;

    float dn = dinv[n];
    float ss = dn * dn;
    f8 s8 = unpack8(Tb[(size_t)n * 16 + q]);
    float acc[8];
#pragma unroll
    for (int j = 0; j < 8; ++j) acc[j] = s8.v[j] * ss;

    int beg = row_ptr[n], end = row_ptr[n + 1];
    int i = beg;
    for (; i + 3 < end; i += 4) {
        int c0 = ecol[i], c1 = ecol[i + 1], c2 = ecol[i + 2], c3 = ecol[i + 3];
        float w0 = dn * dinv[c0];
        float w1 = dn * dinv[c1];
        float w2 = dn * dinv[c2];
        float w3 = dn * dinv[c3];
        uint4 g0 = Tb[(size_t)c0 * 16 + q];
        uint4 g1 = Tb[(size_t)c1 * 16 + q];
        uint4 g2 = Tb[(size_t)c2 * 16 + q];
        uint4 g3 = Tb[(size_t)c3 * 16 + q];
        f8 a0 = unpack8(g0);
        f8 a1 = unpack8(g1);
        f8 a2 = unpack8(g2);
        f8 a3 = unpack8(g3);
#pragma unroll
        for (int j = 0; j < 8; ++j) acc[j] = fmaf(w0, a0.v[j], acc[j]);
#pragma unroll
        for (int j = 0; j < 8; ++j) acc[j] = fmaf(w1, a1.v[j], acc[j]);
#pragma unroll
        for (int j = 0; j < 8; ++j) acc[j] = fmaf(w2, a2.v[j], acc[j]);
#pragma unroll
        for (int j = 0; j < 8; ++j) acc[j] = fmaf(w3, a3.v[j], acc[j]);
    }
    for (; i < end; ++i) {
        int c0 = ecol[i];
        float w0 = dn * dinv[c0];
        f8 a0 = unpack8(Tb[(size_t)c0 * 16 + q]);
#pragma unroll
        for (int j = 0; j < 8; ++j) acc[j] = fmaf(w0, a0.v[j], acc[j]);
    }

    float4 b0 = ((const float4*)b)[q * 2];
    float4 b1v = ((const float4*)b)[q * 2 + 1];
    acc[0] = fmaxf(acc[0] + b0.x, 0.f);
    acc[1] = fmaxf(acc[1] + b0.y, 0.f);
    acc[2] = fmaxf(acc[2] + b0.z, 0.f);
    acc[3] = fmaxf(acc[3] + b0.w, 0.f);
    acc[4] = fmaxf(acc[4] + b1v.x, 0.f);
    acc[5] = fmaxf(acc[5] + b1v.y, 0.f);
    acc[6] = fmaxf(acc[6] + b1v.z, 0.f);
    acc[7] = fmaxf(acc[7] + b1v.w, 0.f);

    uint4 o;
    o.x = pack2(acc[0], acc[1]);
    o.y = pack2(acc[2], acc[3]);
    o.z = pack2(acc[4], acc[5]);
    o.w = pack2(acc[6], acc[7]);
    Ub[(size_t)n * 16 + q] = o;
}

// H2[N,40](bf16) = U[N,128](bf16) @ W2[128,40]. One thread: 2 nodes x 40 classes.
__global__ __launch_bounds__(256) void k_gemm2(const uint4* __restrict__ Ub,
                                               const float* __restrict__ W2,
                                               uint4* __restrict__ H2b, int N) {
    __shared__ float Wl[128 * 40];
    int t = threadIdx.x;
    float4* Wl4 = (float4*)Wl;
    const float4* W4 = (const float4*)W2;
#pragma unroll
    for (int i = 0; i < 5; ++i) Wl4[t + 256 * i] = W4[t + 256 * i];
    __syncthreads();

    int n0 = blockIdx.x * 512 + t;
    int n1 = n0 + 256;
    int n0c = n0 < N ? n0 : N - 1;
    int n1c = n1 < N ? n1 : N - 1;
    float a0[40], a1[40];
#pragma unroll
    for (int c = 0; c < 40; ++c) { a0[c] = 0.f; a1[c] = 0.f; }

    for (int k8 = 0; k8 < 16; ++k8) {
        f8 xa = unpack8(Ub[(size_t)n0c * 16 + k8]);
        f8 xb = unpack8(Ub[(size_t)n1c * 16 + k8]);
#pragma unroll
        for (int j = 0; j < 8; ++j) {
            float xaj = xa.v[j];
            float xbj = xb.v[j];
            int k = k8 * 8 + j;
#pragma unroll
            for (int cq = 0; cq < 10; ++cq) {
                float4 w = Wl4[k * 10 + cq];
                a0[cq * 4 + 0] = fmaf(xaj, w.x, a0[cq * 4 + 0]);
                a0[cq * 4 + 1] = fmaf(xaj, w.y, a0[cq * 4 + 1]);
                a0[cq * 4 + 2] = fmaf(xaj, w.z, a0[cq * 4 + 2]);
                a0[cq * 4 + 3] = fmaf(xaj, w.w, a0[cq * 4 + 3]);
                a1[cq * 4 + 0] = fmaf(xbj, w.x, a1[cq * 4 + 0]);
                a1[cq * 4 + 1] = fmaf(xbj, w.y, a1[cq * 4 + 1]);
                a1[cq * 4 + 2] = fmaf(xbj, w.z, a1[cq * 4 + 2]);
                a1[cq * 4 + 3] = fmaf(xbj, w.w, a1[cq * 4 + 3]);
            }
        }
    }
    if (n0 < N) {
#pragma unroll
        for (int g = 0; g < 5; ++g) {
            uint4 o;
            o.x = pack2(a0[g * 8 + 0], a0[g * 8 + 1]);
            o.y = pack2(a0[g * 8 + 2], a0[g * 8 + 3]);
            o.z = pack2(a0[g * 8 + 4], a0[g * 8 + 5]);
            o.w = pack2(a0[g * 8 + 6], a0[g * 8 + 7]);
            H2b[(size_t)n0 * 5 + g] = o;
        }
    }
    if (n1 < N) {
#pragma unroll
        for (int g = 0; g < 5; ++g) {
            uint4 o;
            o.x = pack2(a1[g * 8 + 0], a1[g * 8 + 1]);
            o.y = pack2(a1[g * 8 + 2], a1[g * 8 + 3]);
            o.z = pack2(a1[g * 8 + 4], a1[g * 8 + 5]);
            o.w = pack2(a1[g * 8 + 6], a1[g * 8 + 7]);
            H2b[(size_t)n1 * 5 + g] = o;
        }
    }
}

// out[n] = log_softmax( dinv^2*H2[n] + sum dinv[n]*dinv[c]*H2[c] + b2 )
// 8 lanes/node; lanes q<5 hold 8 classes each (uint4 of bf16).
__global__ __launch_bounds__(256) void k_pull2(const uint4* __restrict__ H2b,
                                               const float* __restrict__ dinv,
                                               const int* __restrict__ row_ptr,
                                               const int* __restrict__ ecol,
                                               const float* __restrict__ b2,
                                               float* __restrict__ out, int N) {
    int tid = blockIdx.x * 256 + threadIdx.x;
    int n = tid >> 3;
    if (n >= N) return;
    int q = tid & 7;
    bool act = q < 5;

    float dn = dinv[n];
    float ss = dn * dn;
    float acc[8];
#pragma unroll
    for (int j = 0; j < 8; ++j) acc[j] = 0.f;
    if (act) {
        f8 s8 = unpack8(H2b[(size_t)n * 5 + q]);
#pragma unroll
        for (int j = 0; j < 8; ++j) acc[j] = s8.v[j] * ss;
    }
    int beg = row_ptr[n], end = row_ptr[n + 1];
    for (int i = beg; i < end; ++i) {
        int c = ecol[i];
        float w = dn * dinv[c];
        if (act) {
            f8 a = unpack8(H2b[(size_t)c * 5 + q]);
#pragma unroll
            for (int j = 0; j < 8; ++j) acc[j] = fmaf(w, a.v[j], acc[j]);
        }
    }
    if (act) {
        float4 b0 = ((const float4*)b2)[q * 2];
        float4 b1v = ((const float4*)b2)[q * 2 + 1];
        acc[0] += b0.x; acc[1] += b0.y; acc[2] += b0.z; acc[3] += b0.w;
        acc[4] += b1v.x; acc[5] += b1v.y; acc[6] += b1v.z; acc[7] += b1v.w;
    }
    float m = -INFINITY;
    if (act) {
#pragma unroll
        for (int j = 0; j < 8; ++j) m = fmaxf(m, acc[j]);
    }
#pragma unroll
    for (int o = 4; o > 0; o >>= 1) m = fmaxf(m, __shfl_xor(m, o, 8));
    float e = 0.f;
    if (act) {
#pragma unroll
        for (int j = 0; j < 8; ++j) e += expf(acc[j] - m);
    }
#pragma unroll
    for (int o = 4; o > 0; o >>= 1) e += __shfl_xor(e, o, 8);
    float lg = m + logf(e);
    if (act) {
        float4* o4 = (float4*)out;
        o4[(size_t)n * 10 + q * 2] =
            make_float4(acc[0] - lg, acc[1] - lg, acc[2] - lg, acc[3] - lg);
        o4[(size_t)n * 10 + q * 2 + 1] =
            make_float4(acc[4] - lg, acc[5] - lg, acc[6] - lg, acc[7] - lg);
    }
}

extern "C" void kernel_launch(void* const* d_in, const int* in_sizes, int n_in,
                              void* d_out, int out_size, void* d_ws, size_t ws_size,
                              hipStream_t stream) {
    const float* x  = (const float*)d_in[0];
    const int*   ei = (const int*)d_in[1];   // integer inputs arrive as int32
    const float* W1 = (const float*)d_in[2];
    const float* b1 = (const float*)d_in[3];
    const float* W2 = (const float*)d_in[4];
    const float* b2 = (const float*)d_in[5];
    float* out = (float*)d_out;

    const int N = in_sizes[0] / 128;  // 100000
    const int E = in_sizes[1] / 2;    // 1600000
    const int nbkt = (N + RB - 1) / RB;  // 1021 (<= 1024 required)

    // workspace layout (~83 MB)
    char* ws = (char*)d_ws;
    int*   deg     = (int*)(ws);                          // N ints
    float* dinv    = (float*)(ws + (512 << 10));          // N f32
    int*   row_ptr = (int*)(ws + (1 << 20));              // N+1
    int*   bsum    = (int*)(ws + (1536 << 10));           // <=1024
    int*   tmp     = (int*)(ws + (1600 << 10));           // N ints
    int*   bktcnt  = (int*)(ws + (2100 << 10));           // 1024
    int*   gcur    = (int*)(ws + (2100 << 10) + 4096);    // 1024
    int*   gbase   = (int*)(ws + (2100 << 10) + 8192);    // 1025
    int*   ecol    = (int*)(ws + (3 << 20));              // E ints = 6.4 MB
    int2*  brec    = (int2*)(ws + (10 << 20));            // E int2 = 12.8 MB
    uint4* H2b     = (uint4*)(ws + (23 << 20));           // N*40 bf16 = 8 MB
    unsigned* Tb   = (unsigned*)(ws + (31 << 20));        // N*128 bf16 = 25.6 MB
    uint4* Ub      = (uint4*)(ws + (57 << 20));           // N*128 bf16 = 25.6 MB

    int nb = (N + 255) / 256;
    int na = (E + TILE_A - 1) / TILE_A;

    k_zero<<<4, 256, 0, stream>>>(bktcnt, 1024);
    k_prebin<<<na, 256, 0, stream>>>(ei, bktcnt, E, nbkt);
    k_bscan<<<1, 1024, 0, stream>>>(bktcnt, gbase, gcur, nbkt);
    k_binA<<<na, 256, 0, stream>>>(ei, gcur, brec, E);
    k_count3<<<nbkt, 256, 0, stream>>>(brec, gbase, deg, N);
    k_scan1<<<nb, 256, 0, stream>>>(deg, tmp, bsum, dinv, N);
    k_scan2<<<1, 1024, 0, stream>>>(bsum, nb);
    k_scan3<<<nb, 256, 0, stream>>>(deg, tmp, bsum, row_ptr, N, E);
    k_csr3<<<nbkt, 256, 0, stream>>>(brec, gbase, row_ptr, ecol, N);

    k_gemm1<<<(N + 31) / 32, 256, 0, stream>>>(x, W1, Tb, N);
    k_pull1<<<((long long)N * 16 + 255) / 256, 256, 0, stream>>>(
        (const uint4*)Tb, dinv, row_ptr, ecol, b1, Ub, N);
    k_gemm2<<<(N + 511) / 512, 256, 0, stream>>>(Ub, W2, H2b, N);
    k_pull2<<<((long long)N * 8 + 255) / 256, 256, 0, stream>>>(
        H2b, dinv, row_ptr, ecol, b2, out, N);
}

// Round 12
// 235.285 us; speedup vs baseline: 1.1809x; 1.1790x over previous
//
#include <hip/hip_runtime.h>
#include <hip/hip_bf16.h>
#include <math.h>

// ---------------------------------------------------------------------------
// GCN 2-layer forward on MI355X (gfx950).
// Inputs: x[N,128] f32, edge_index[2,E] int32, W1[128,128], b1[128],
//         W2[128,40], b2[40].  Output: log_softmax [N,40] f32.
// Round 12: MFMA GEMMs. k_gemm1 was a VALU fp32 GEMM (MfmaUtil=0, VALUBusy
//   60%, 3x off the 21us fp32-FMA floor, occupancy capped by 80KB LDS).
//   Replaced with mfma_f32_16x16x32_bf16: A-frags straight from global x
//   (f32->bf16 inline; zero cross-block reuse so no LDS), B-frags from
//   pre-transposed bf16 Wt[f][k] (L1-resident, 16B contiguous loads).
//   Layouts per verified guide claims (m89): A row=l&15,k=(l>>4)*8+j;
//   C/D col=l&15,row=(l>>4)*4+reg. gemm2 same structure, 40 cls padded to 48.
//   CSR build (counting sort, LDS cursors) and pull kernels unchanged.
// ---------------------------------------------------------------------------

#define TILE_A 8192   // edges per binning block
#define RB 98         // rows per bucket (1021 buckets for N=100000)

typedef __attribute__((ext_vector_type(8))) short bf16x8;   // 8 bf16 = 4 VGPR
typedef __attribute__((ext_vector_type(4))) float f32x4;

struct f8 { float v[8]; };

__device__ inline f8 unpack8(uint4 u) {
    f8 r;
    r.v[0] = __uint_as_float(u.x << 16);
    r.v[1] = __uint_as_float(u.x & 0xffff0000u);
    r.v[2] = __uint_as_float(u.y << 16);
    r.v[3] = __uint_as_float(u.y & 0xffff0000u);
    r.v[4] = __uint_as_float(u.z << 16);
    r.v[5] = __uint_as_float(u.z & 0xffff0000u);
    r.v[6] = __uint_as_float(u.w << 16);
    r.v[7] = __uint_as_float(u.w & 0xffff0000u);
    return r;
}

__device__ inline unsigned pack2(float a, float b) {  // a -> low half (RNE)
    __hip_bfloat16 ha = __float2bfloat16(a);
    __hip_bfloat16 hb = __float2bfloat16(b);
    unsigned short sa = *(unsigned short*)&ha;
    unsigned short sb = *(unsigned short*)&hb;
    return (unsigned)sa | ((unsigned)sb << 16);
}

__device__ inline short bfs(float f) {  // f32 -> bf16 bits (RNE)
    __hip_bfloat16 h = __float2bfloat16(f);
    return *(short*)&h;
}

__device__ inline bf16x8 to8(float4 p, float4 q) {
    bf16x8 v;
    v[0] = bfs(p.x); v[1] = bfs(p.y); v[2] = bfs(p.z); v[3] = bfs(p.w);
    v[4] = bfs(q.x); v[5] = bfs(q.y); v[6] = bfs(q.z); v[7] = bfs(q.w);
    return v;
}

__global__ __launch_bounds__(256) void k_zero(int* __restrict__ p, int n) {
    int i = blockIdx.x * 256 + threadIdx.x;
    if (i < n) p[i] = 0;
}

// bucket histogram over row index (LDS-aggregated)
__global__ __launch_bounds__(256) void k_prebin(const int* __restrict__ row,
                                                int* __restrict__ bktcnt,
                                                int E, int nbkt) {
    __shared__ int h[1024];
    int t = threadIdx.x;
    for (int j = t; j < 1024; j += 256) h[j] = 0;
    __syncthreads();
    int base = blockIdx.x * TILE_A;
    int lim = min(base + TILE_A, E);
    for (int i = base + t; i < lim; i += 256) atomicAdd(&h[row[i] / RB], 1);
    __syncthreads();
    for (int j = t; j < nbkt; j += 256)
        if (h[j]) atomicAdd(&bktcnt[j], h[j]);
}

// single-block scan of bucket counts -> gbase (exclusive), gcur (= gbase)
__global__ __launch_bounds__(1024) void k_bscan(const int* __restrict__ bktcnt,
                                                int* __restrict__ gbase,
                                                int* __restrict__ gcur, int nbkt) {
    __shared__ int l[1024];
    int t = threadIdx.x;
    int v = (t < nbkt) ? bktcnt[t] : 0;
    l[t] = v;
    __syncthreads();
#pragma unroll
    for (int o = 1; o < 1024; o <<= 1) {
        int u = (t >= o) ? l[t - o] : 0;
        __syncthreads();
        l[t] += u;
        __syncthreads();
    }
    if (t < nbkt) {
        int excl = l[t] - v;
        gbase[t] = excl;
        gcur[t] = excl;
        if (t == nbkt - 1) gbase[nbkt] = l[t];
    }
}

// partition edges into buckets as (r,c) records; LDS histogram ->
// one global tail-append atomic per (block, bucket) -> LDS cursor scatter.
__global__ __launch_bounds__(256) void k_binA(const int* __restrict__ ei,
                                              int* __restrict__ gcur,
                                              int2* __restrict__ brec, int E) {
    __shared__ int h[1024];
    __shared__ int cur[1024];
    int t = threadIdx.x;
    for (int j = t; j < 1024; j += 256) h[j] = 0;
    __syncthreads();
    int base = blockIdx.x * TILE_A;
    int lim = min(base + TILE_A, E);
    for (int i = base + t; i < lim; i += 256) atomicAdd(&h[ei[i] / RB], 1);
    __syncthreads();
    for (int j = t; j < 1024; j += 256)
        cur[j] = h[j] ? atomicAdd(&gcur[j], h[j]) : 0;
    __syncthreads();
    for (int i = base + t; i < lim; i += 256) {
        int r = ei[i];
        int pos = atomicAdd(&cur[r / RB], 1);
        brec[pos] = make_int2(r, ei[E + i]);
    }
}

// per-bucket degree count: LDS histogram, coalesced non-atomic deg write (+1 self loop)
__global__ __launch_bounds__(256) void k_count3(const int2* __restrict__ brec,
                                                const int* __restrict__ gbase,
                                                int* __restrict__ deg, int N) {
    __shared__ int h[RB];
    int k = blockIdx.x;
    int t = threadIdx.x;
    if (t < RB) h[t] = 0;
    __syncthreads();
    int s = gbase[k], e = gbase[k + 1];
    int r0 = k * RB;
    for (int i = s + t; i < e; i += 256) atomicAdd(&h[brec[i].x - r0], 1);
    __syncthreads();
    if (t < RB && r0 + t < N) deg[r0 + t] = h[t] + 1;
}

// block-level inclusive scan of (deg-1); partials to bsum; also dinv = rsqrt(deg)
__global__ __launch_bounds__(256) void k_scan1(const int* __restrict__ deg,
                                               int* __restrict__ tmp,
                                               int* __restrict__ bsum,
                                               float* __restrict__ dinv, int N) {
    __shared__ int l[256];
    int t = threadIdx.x;
    int i = blockIdx.x * 256 + t;
    int d = (i < N) ? deg[i] : 1;
    if (i < N) dinv[i] = rsqrtf((float)d);
    l[t] = (i < N) ? d - 1 : 0;
    __syncthreads();
#pragma unroll
    for (int o = 1; o < 256; o <<= 1) {
        int u = (t >= o) ? l[t - o] : 0;
        __syncthreads();
        l[t] += u;
        __syncthreads();
    }
    if (i < N) tmp[i] = l[t];
    if (t == 255) bsum[blockIdx.x] = l[255];
}

__global__ __launch_bounds__(1024) void k_scan2(int* __restrict__ bsum, int nb) {
    __shared__ int l[1024];
    int t = threadIdx.x;
    l[t] = (t < nb) ? bsum[t] : 0;
    __syncthreads();
#pragma unroll
    for (int o = 1; o < 1024; o <<= 1) {
        int u = (t >= o) ? l[t - o] : 0;
        __syncthreads();
        l[t] += u;
        __syncthreads();
    }
    if (t < nb) bsum[t] = l[t];
}

__global__ __launch_bounds__(256) void k_scan3(const int* __restrict__ deg,
                                               const int* __restrict__ tmp,
                                               const int* __restrict__ bsum,
                                               int* __restrict__ row_ptr, int N, int E) {
    int i = blockIdx.x * 256 + threadIdx.x;
    if (i >= N) return;
    int excl = tmp[i] - (deg[i] - 1) + (blockIdx.x ? bsum[blockIdx.x - 1] : 0);
    row_ptr[i] = excl;
    if (i == 0) row_ptr[N] = E;
}

// per-bucket CSR scatter: cursors in LDS, writes confined to the bucket's
// contiguous ecol window (~6KB) -> streaming, no global atomics.
__global__ __launch_bounds__(256) void k_csr3(const int2* __restrict__ brec,
                                              const int* __restrict__ gbase,
                                              const int* __restrict__ row_ptr,
                                              int* __restrict__ ecol, int N) {
    __shared__ int cur[RB];
    int k = blockIdx.x;
    int t = threadIdx.x;
    int r0 = k * RB;
    if (t < RB) cur[t] = (r0 + t < N) ? row_ptr[r0 + t] : 0;
    __syncthreads();
    int s = gbase[k], e = gbase[k + 1];
    for (int i = s + t; i < e; i += 256) {
        int2 rc = brec[i];
        int pos = atomicAdd(&cur[rc.x - r0], 1);
        ecol[pos] = rc.y;
    }
}

// Wt1[f][k] = bf16(W1[k][f])  (128x128)
__global__ __launch_bounds__(256) void k_wt1(const float* __restrict__ W,
                                             short* __restrict__ Wt) {
    int idx = blockIdx.x * 256 + threadIdx.x;  // 16384
    int k = idx >> 7, f = idx & 127;
    Wt[f * 128 + k] = bfs(W[k * 128 + f]);
}

// Wt2[f][k] = bf16(W2[k][f]) for f<40, else 0  (48x128, padded)
__global__ __launch_bounds__(256) void k_wt2(const float* __restrict__ W,
                                             short* __restrict__ Wt) {
    int idx = blockIdx.x * 256 + threadIdx.x;  // 6144
    int f = idx >> 7, k = idx & 127;
    Wt[idx] = (f < 40) ? bfs(W[k * 40 + f]) : (short)0;
}

// T[N,128](bf16) = bf16(X) @ bf16(W1) via MFMA. 128 nodes/block, 4 waves;
// wave handles 32 nodes (2 groups of 16) x 128 feats (8 tiles of 16).
__global__ __launch_bounds__(256) void k_gemm1m(const float* __restrict__ x,
                                                const short* __restrict__ Wt,  // [128f][128k]
                                                short* __restrict__ Tb, int N) {
    int t = threadIdx.x;
    int wid = t >> 6, l = t & 63;
    int r = l & 15;          // A row / B col / D col
    int ko = (l >> 4) * 8;   // k offset within 32-chunk
    long long nb = (long long)blockIdx.x * 128 + wid * 32;

    bf16x8 a[2][4];
#pragma unroll
    for (int g = 0; g < 2; ++g) {
        long long n = nb + g * 16 + r;
        if (n >= N) n = N - 1;
        const float* xr = x + n * 128;
#pragma unroll
        for (int kc = 0; kc < 4; ++kc) {
            float4 p = *(const float4*)(xr + kc * 32 + ko);
            float4 q = *(const float4*)(xr + kc * 32 + ko + 4);
            a[g][kc] = to8(p, q);
        }
    }

    f32x4 acc[2][8];
#pragma unroll
    for (int g = 0; g < 2; ++g)
#pragma unroll
        for (int ft = 0; ft < 8; ++ft) acc[g][ft] = (f32x4){0.f, 0.f, 0.f, 0.f};

#pragma unroll
    for (int ft = 0; ft < 8; ++ft) {
        const short* wp = Wt + (ft * 16 + r) * 128 + ko;
#pragma unroll
        for (int kc = 0; kc < 4; ++kc) {
            bf16x8 b = *(const bf16x8*)(wp + kc * 32);
            acc[0][ft] = __builtin_amdgcn_mfma_f32_16x16x32_bf16(a[0][kc], b, acc[0][ft], 0, 0, 0);
            acc[1][ft] = __builtin_amdgcn_mfma_f32_16x16x32_bf16(a[1][kc], b, acc[1][ft], 0, 0, 0);
        }
    }

    int row0 = (l >> 4) * 4;  // D: col=r, row=row0+i
#pragma unroll
    for (int g = 0; g < 2; ++g) {
#pragma unroll
        for (int i = 0; i < 4; ++i) {
            long long n = nb + g * 16 + row0 + i;
            if (n < N) {
                short* orow = Tb + n * 128;
#pragma unroll
                for (int ft = 0; ft < 8; ++ft) orow[ft * 16 + r] = bfs(acc[g][ft][i]);
            }
        }
    }
}

// H2[N,40](bf16) = U[N,128](bf16) @ bf16(W2) via MFMA. Same tiling, 3 f-tiles.
__global__ __launch_bounds__(256) void k_gemm2m(const short* __restrict__ Ub,   // [N][128] bf16
                                                const short* __restrict__ Wt2,  // [48f][128k]
                                                short* __restrict__ H2b, int N) {
    int t = threadIdx.x;
    int wid = t >> 6, l = t & 63;
    int r = l & 15;
    int ko = (l >> 4) * 8;
    long long nb = (long long)blockIdx.x * 128 + wid * 32;

    bf16x8 a[2][4];
#pragma unroll
    for (int g = 0; g < 2; ++g) {
        long long n = nb + g * 16 + r;
        if (n >= N) n = N - 1;
        const short* ur = Ub + n * 128;
#pragma unroll
        for (int kc = 0; kc < 4; ++kc)
            a[g][kc] = *(const bf16x8*)(ur + kc * 32 + ko);
    }

    f32x4 acc[2][3];
#pragma unroll
    for (int g = 0; g < 2; ++g)
#pragma unroll
        for (int ft = 0; ft < 3; ++ft) acc[g][ft] = (f32x4){0.f, 0.f, 0.f, 0.f};

#pragma unroll
    for (int ft = 0; ft < 3; ++ft) {
        const short* wp = Wt2 + (ft * 16 + r) * 128 + ko;
#pragma unroll
        for (int kc = 0; kc < 4; ++kc) {
            bf16x8 b = *(const bf16x8*)(wp + kc * 32);
            acc[0][ft] = __builtin_amdgcn_mfma_f32_16x16x32_bf16(a[0][kc], b, acc[0][ft], 0, 0, 0);
            acc[1][ft] = __builtin_amdgcn_mfma_f32_16x16x32_bf16(a[1][kc], b, acc[1][ft], 0, 0, 0);
        }
    }

    int row0 = (l >> 4) * 4;
#pragma unroll
    for (int g = 0; g < 2; ++g) {
#pragma unroll
        for (int i = 0; i < 4; ++i) {
            long long n = nb + g * 16 + row0 + i;
            if (n < N) {
                short* orow = H2b + n * 40;
#pragma unroll
                for (int ft = 0; ft < 3; ++ft) {
                    int f = ft * 16 + r;
                    if (f < 40) orow[f] = bfs(acc[g][ft][i]);
                }
            }
        }
    }
}

// U[n](bf16) = relu( dinv^2*T[n] + sum_e dinv[n]*dinv[c]*T[c] + b1 )
// 16 lanes/node, 8 bf16 features per lane (uint4); edge loop 4x unrolled.
__global__ __launch_bounds__(256) void k_pull1(const uint4* __restrict__ Tb,
                                               const float* __restrict__ dinv,
                                               const int* __restrict__ row_ptr,
                                               const int* __restrict__ ecol,
                                               const float* __restrict__ b,
                                               uint4* __restrict__ Ub, int N) {
    int tid = blockIdx.x * 256 + threadIdx.x;
    int n = tid >> 4;
    if (n >= N) return;
    int q = tid & 15;

    float dn = dinv[n];
    float ss = dn * dn;
    f8 s8 = unpack8(Tb[(size_t)n * 16 + q]);
    float acc[8];
#pragma unroll
    for (int j = 0; j < 8; ++j) acc[j] = s8.v[j] * ss;

    int beg = row_ptr[n], end = row_ptr[n + 1];
    int i = beg;
    for (; i + 3 < end; i += 4) {
        int c0 = ecol[i], c1 = ecol[i + 1], c2 = ecol[i + 2], c3 = ecol[i + 3];
        float w0 = dn * dinv[c0];
        float w1 = dn * dinv[c1];
        float w2 = dn * dinv[c2];
        float w3 = dn * dinv[c3];
        uint4 g0 = Tb[(size_t)c0 * 16 + q];
        uint4 g1 = Tb[(size_t)c1 * 16 + q];
        uint4 g2 = Tb[(size_t)c2 * 16 + q];
        uint4 g3 = Tb[(size_t)c3 * 16 + q];
        f8 a0 = unpack8(g0);
        f8 a1 = unpack8(g1);
        f8 a2 = unpack8(g2);
        f8 a3 = unpack8(g3);
#pragma unroll
        for (int j = 0; j < 8; ++j) acc[j] = fmaf(w0, a0.v[j], acc[j]);
#pragma unroll
        for (int j = 0; j < 8; ++j) acc[j] = fmaf(w1, a1.v[j], acc[j]);
#pragma unroll
        for (int j = 0; j < 8; ++j) acc[j] = fmaf(w2, a2.v[j], acc[j]);
#pragma unroll
        for (int j = 0; j < 8; ++j) acc[j] = fmaf(w3, a3.v[j], acc[j]);
    }
    for (; i < end; ++i) {
        int c0 = ecol[i];
        float w0 = dn * dinv[c0];
        f8 a0 = unpack8(Tb[(size_t)c0 * 16 + q]);
#pragma unroll
        for (int j = 0; j < 8; ++j) acc[j] = fmaf(w0, a0.v[j], acc[j]);
    }

    float4 b0 = ((const float4*)b)[q * 2];
    float4 b1v = ((const float4*)b)[q * 2 + 1];
    acc[0] = fmaxf(acc[0] + b0.x, 0.f);
    acc[1] = fmaxf(acc[1] + b0.y, 0.f);
    acc[2] = fmaxf(acc[2] + b0.z, 0.f);
    acc[3] = fmaxf(acc[3] + b0.w, 0.f);
    acc[4] = fmaxf(acc[4] + b1v.x, 0.f);
    acc[5] = fmaxf(acc[5] + b1v.y, 0.f);
    acc[6] = fmaxf(acc[6] + b1v.z, 0.f);
    acc[7] = fmaxf(acc[7] + b1v.w, 0.f);

    uint4 o;
    o.x = pack2(acc[0], acc[1]);
    o.y = pack2(acc[2], acc[3]);
    o.z = pack2(acc[4], acc[5]);
    o.w = pack2(acc[6], acc[7]);
    Ub[(size_t)n * 16 + q] = o;
}

// out[n] = log_softmax( dinv^2*H2[n] + sum dinv[n]*dinv[c]*H2[c] + b2 )
// 8 lanes/node; lanes q<5 hold 8 classes each (uint4 of bf16).
__global__ __launch_bounds__(256) void k_pull2(const uint4* __restrict__ H2b,
                                               const float* __restrict__ dinv,
                                               const int* __restrict__ row_ptr,
                                               const int* __restrict__ ecol,
                                               const float* __restrict__ b2,
                                               float* __restrict__ out, int N) {
    int tid = blockIdx.x * 256 + threadIdx.x;
    int n = tid >> 3;
    if (n >= N) return;
    int q = tid & 7;
    bool act = q < 5;

    float dn = dinv[n];
    float ss = dn * dn;
    float acc[8];
#pragma unroll
    for (int j = 0; j < 8; ++j) acc[j] = 0.f;
    if (act) {
        f8 s8 = unpack8(H2b[(size_t)n * 5 + q]);
#pragma unroll
        for (int j = 0; j < 8; ++j) acc[j] = s8.v[j] * ss;
    }
    int beg = row_ptr[n], end = row_ptr[n + 1];
    for (int i = beg; i < end; ++i) {
        int c = ecol[i];
        float w = dn * dinv[c];
        if (act) {
            f8 a = unpack8(H2b[(size_t)c * 5 + q]);
#pragma unroll
            for (int j = 0; j < 8; ++j) acc[j] = fmaf(w, a.v[j], acc[j]);
        }
    }
    if (act) {
        float4 b0 = ((const float4*)b2)[q * 2];
        float4 b1v = ((const float4*)b2)[q * 2 + 1];
        acc[0] += b0.x; acc[1] += b0.y; acc[2] += b0.z; acc[3] += b0.w;
        acc[4] += b1v.x; acc[5] += b1v.y; acc[6] += b1v.z; acc[7] += b1v.w;
    }
    float m = -INFINITY;
    if (act) {
#pragma unroll
        for (int j = 0; j < 8; ++j) m = fmaxf(m, acc[j]);
    }
#pragma unroll
    for (int o = 4; o > 0; o >>= 1) m = fmaxf(m, __shfl_xor(m, o, 8));
    float e = 0.f;
    if (act) {
#pragma unroll
        for (int j = 0; j < 8; ++j) e += expf(acc[j] - m);
    }
#pragma unroll
    for (int o = 4; o > 0; o >>= 1) e += __shfl_xor(e, o, 8);
    float lg = m + logf(e);
    if (act) {
        float4* o4 = (float4*)out;
        o4[(size_t)n * 10 + q * 2] =
            make_float4(acc[0] - lg, acc[1] - lg, acc[2] - lg, acc[3] - lg);
        o4[(size_t)n * 10 + q * 2 + 1] =
            make_float4(acc[4] - lg, acc[5] - lg, acc[6] - lg, acc[7] - lg);
    }
}

extern "C" void kernel_launch(void* const* d_in, const int* in_sizes, int n_in,
                              void* d_out, int out_size, void* d_ws, size_t ws_size,
                              hipStream_t stream) {
    const float* x  = (const float*)d_in[0];
    const int*   ei = (const int*)d_in[1];   // integer inputs arrive as int32
    const float* W1 = (const float*)d_in[2];
    const float* b1 = (const float*)d_in[3];
    const float* W2 = (const float*)d_in[4];
    const float* b2 = (const float*)d_in[5];
    float* out = (float*)d_out;

    const int N = in_sizes[0] / 128;  // 100000
    const int E = in_sizes[1] / 2;    // 1600000
    const int nbkt = (N + RB - 1) / RB;  // 1021 (<= 1024 required)

    // workspace layout (~83 MB)
    char* ws = (char*)d_ws;
    int*   deg     = (int*)(ws);                          // N ints
    float* dinv    = (float*)(ws + (512 << 10));          // N f32
    int*   row_ptr = (int*)(ws + (1 << 20));              // N+1
    int*   bsum    = (int*)(ws + (1536 << 10));           // <=1024
    int*   tmp     = (int*)(ws + (1600 << 10));           // N ints
    int*   bktcnt  = (int*)(ws + (2100 << 10));           // 1024
    int*   gcur    = (int*)(ws + (2100 << 10) + 4096);    // 1024
    int*   gbase   = (int*)(ws + (2100 << 10) + 8192);    // 1025
    short* Wt1     = (short*)(ws + (2200 << 10));         // 128x128 bf16 = 32 KB
    short* Wt2     = (short*)(ws + (2300 << 10));         // 48x128 bf16 = 12 KB
    int*   ecol    = (int*)(ws + (3 << 20));              // E ints = 6.4 MB
    int2*  brec    = (int2*)(ws + (10 << 20));            // E int2 = 12.8 MB
    uint4* H2b     = (uint4*)(ws + (23 << 20));           // N*40 bf16 = 8 MB
    unsigned* Tb   = (unsigned*)(ws + (31 << 20));        // N*128 bf16 = 25.6 MB
    uint4* Ub      = (uint4*)(ws + (57 << 20));           // N*128 bf16 = 25.6 MB

    int nb = (N + 255) / 256;
    int na = (E + TILE_A - 1) / TILE_A;
    int ng = (N + 127) / 128;  // MFMA gemm blocks

    k_zero<<<4, 256, 0, stream>>>(bktcnt, 1024);
    k_prebin<<<na, 256, 0, stream>>>(ei, bktcnt, E, nbkt);
    k_bscan<<<1, 1024, 0, stream>>>(bktcnt, gbase, gcur, nbkt);
    k_binA<<<na, 256, 0, stream>>>(ei, gcur, brec, E);
    k_count3<<<nbkt, 256, 0, stream>>>(brec, gbase, deg, N);
    k_scan1<<<nb, 256, 0, stream>>>(deg, tmp, bsum, dinv, N);
    k_scan2<<<1, 1024, 0, stream>>>(bsum, nb);
    k_scan3<<<nb, 256, 0, stream>>>(deg, tmp, bsum, row_ptr, N, E);
    k_csr3<<<nbkt, 256, 0, stream>>>(brec, gbase, row_ptr, ecol, N);

    k_wt1<<<64, 256, 0, stream>>>(W1, Wt1);
    k_wt2<<<24, 256, 0, stream>>>(W2, Wt2);

    k_gemm1m<<<ng, 256, 0, stream>>>(x, Wt1, (short*)Tb, N);
    k_pull1<<<((long long)N * 16 + 255) / 256, 256, 0, stream>>>(
        (const uint4*)Tb, dinv, row_ptr, ecol, b1, Ub, N);
    k_gemm2m<<<ng, 256, 0, stream>>>((const short*)Ub, Wt2, (short*)H2b, N);
    k_pull2<<<((long long)N * 8 + 255) / 256, 256, 0, stream>>>(
        H2b, dinv, row_ptr, ecol, b2, out, N);
}